// Round 4
// baseline (1235.214 us; speedup 1.0000x reference)
//
#include <hip/hip_runtime.h>

constexpr int H    = 128;
constexpr int NN   = 10000;
constexpr int EE   = 160000;
constexpr int RCN  = 4;      // R*C
constexpr int NG   = 64;     // graphs per replica
constexpr int OUTF = 64;
constexpr int DSEG = 256;    // RCN*NG
constexpr int LDA  = 130;    // padded LDS row stride (floats); 128x130x4 = 65 KB -> 2 blocks/CU

__device__ __forceinline__ float gelu_f(float x){
  return 0.5f*x*(1.0f + erff(x*0.70710678118654752440f));
}

__device__ __forceinline__ void fma4(float acc[4], float4 a, const float4 w[4]){
  acc[0] += a.x*w[0].x + a.y*w[1].x + a.z*w[2].x + a.w*w[3].x;
  acc[1] += a.x*w[0].y + a.y*w[1].y + a.z*w[2].y + a.w*w[3].y;
  acc[2] += a.x*w[0].z + a.y*w[1].z + a.z*w[2].z + a.w*w[3].z;
  acc[3] += a.x*w[0].w + a.y*w[1].w + a.z*w[2].w + a.w*w[3].w;
}

// ---------- edge mask
__global__ void k_edge_mask(const int* __restrict__ src, const int* __restrict__ dst,
                            const float* __restrict__ nm, float4* __restrict__ em4){
  int e = blockIdx.x*256 + threadIdx.x;
  if(e >= EE) return;
  int s = src[e], d = dst[e];
  float4 m;
  m.x = nm[0*NN+s]*nm[0*NN+d];
  m.y = nm[1*NN+s]*nm[1*NN+d];
  m.z = nm[2*NN+s]*nm[2*NN+d];
  m.w = nm[3*NN+s]*nm[3*NN+d];
  em4[e] = m;
}

// ---------- CSR build
__global__ void k_hist(const int* __restrict__ dst, int* __restrict__ cnt){
  int e = blockIdx.x*256 + threadIdx.x;
  if(e < EE) atomicAdd(&cnt[dst[e]], 1);
}

__global__ __launch_bounds__(1024) void k_scan(const int* __restrict__ cnt,
                                               int* __restrict__ rs, int* __restrict__ cur){
  __shared__ int part[1024];
  int t = threadIdx.x;
  const int CH = 10;
  int base = t*CH;
  int s = 0;
  #pragma unroll
  for(int j=0;j<CH;j++){ int i = base+j; if(i<NN) s += cnt[i]; }
  part[t] = s;
  __syncthreads();
  for(int off=1; off<1024; off<<=1){
    int v = (t>=off) ? part[t-off] : 0;
    __syncthreads();
    part[t] += v;
    __syncthreads();
  }
  int run = (t==0) ? 0 : part[t-1];
  #pragma unroll
  for(int j=0;j<CH;j++){
    int i = base+j;
    if(i<NN){ rs[i] = run; cur[i] = run; run += cnt[i]; }
  }
  if(t == 1023) rs[NN] = part[1023];
}

__global__ void k_fill(const int* __restrict__ dst,
                       int* __restrict__ cur, int* __restrict__ eid){
  int e = blockIdx.x*256 + threadIdx.x;
  if(e >= EE) return;
  int p = atomicAdd(&cur[dst[e]], 1);
  eid[p] = e;
}

__global__ void k_sortcsr(const int* __restrict__ rs, int* __restrict__ eid,
                          const int* __restrict__ src, int* __restrict__ esrc){
  int n = blockIdx.x*256 + threadIdx.x;
  if(n >= NN) return;
  int jb = rs[n], je = rs[n+1];
  for(int j=jb+1; j<je; j++){
    int v = eid[j];
    int k = j-1;
    while(k >= jb && eid[k] > v){ eid[k+1] = eid[k]; k--; }
    eid[k+1] = v;
  }
  for(int j=jb; j<je; j++) esrc[j] = src[eid[j]];
}

__global__ void k_gbounds(const int* __restrict__ batch, int* __restrict__ gs){
  int g = threadIdx.x;
  if(g > NG) return;
  if(g == NG){ gs[NG] = NN; return; }
  int lo = 0, hi = NN;
  while(lo < hi){
    int mid = (lo+hi)>>1;
    if(batch[mid] < g) lo = mid+1; else hi = mid;
  }
  gs[g] = lo;
}

// ---------- emb = edge_attr @ W + b : 128x128 tile, A in LDS, W from global (L2-hot)
__global__ __launch_bounds__(256) void k_emb(const float* __restrict__ A, const float* __restrict__ W,
                       const float* __restrict__ bias, float* __restrict__ emb){
  __shared__ float Al[128*LDA];   // 65 KB -> 2 blocks/CU
  int t = threadIdx.x;
  {
    const float4* a4 = (const float4*)(A + (size_t)blockIdx.x*128*H);
    #pragma unroll
    for(int i=0;i<16;i++){
      int idx = t + i*256;
      int r = idx >> 5, c4 = idx & 31;
      *(float4*)&Al[r*LDA + c4*4] = a4[idx];
    }
  }
  __syncthreads();
  int tx = t & 15, ty = t >> 4;
  int c0 = tx*4, c1 = c0 + 64;
  int r0 = ty*4, r1 = r0 + 64;
  float acc[2][2][4][4] = {};
  #pragma unroll 2
  for(int k=0;k<H;k+=4){
    float4 wA[4], wB[4];
    #pragma unroll
    for(int kk=0;kk<4;kk++){
      wA[kk] = *(const float4*)&W[(k+kk)*H + c0];
      wB[kk] = *(const float4*)&W[(k+kk)*H + c1];
    }
    float4 aA[4], aB[4];
    #pragma unroll
    for(int i=0;i<4;i++){
      aA[i] = *(const float4*)&Al[(r0+i)*LDA + k];
      aB[i] = *(const float4*)&Al[(r1+i)*LDA + k];
    }
    #pragma unroll
    for(int i=0;i<4;i++){
      fma4(acc[0][0][i], aA[i], wA);
      fma4(acc[0][1][i], aA[i], wB);
      fma4(acc[1][0][i], aB[i], wA);
      fma4(acc[1][1][i], aB[i], wB);
    }
  }
  float4 bv0 = *(const float4*)&bias[c0];
  float4 bv1 = *(const float4*)&bias[c1];
  float* ob = emb + (size_t)blockIdx.x*128*H;
  #pragma unroll
  for(int i=0;i<4;i++){
    float4 o;
    o.x=acc[0][0][i][0]+bv0.x; o.y=acc[0][0][i][1]+bv0.y; o.z=acc[0][0][i][2]+bv0.z; o.w=acc[0][0][i][3]+bv0.w;
    *(float4*)&ob[(r0+i)*H + c0] = o;
    o.x=acc[0][1][i][0]+bv1.x; o.y=acc[0][1][i][1]+bv1.y; o.z=acc[0][1][i][2]+bv1.z; o.w=acc[0][1][i][3]+bv1.w;
    *(float4*)&ob[(r0+i)*H + c1] = o;
    o.x=acc[1][0][i][0]+bv0.x; o.y=acc[1][0][i][1]+bv0.y; o.z=acc[1][0][i][2]+bv0.z; o.w=acc[1][0][i][3]+bv0.w;
    *(float4*)&ob[(r1+i)*H + c0] = o;
    o.x=acc[1][1][i][0]+bv1.x; o.y=acc[1][1][i][1]+bv1.y; o.z=acc[1][1][i][2]+bv1.z; o.w=acc[1][1][i][3]+bv1.w;
    *(float4*)&ob[(r1+i)*H + c1] = o;
  }
}

// ---------- aggregation: one wave per node; lane half selects rc pair
template<bool FIRST>
__global__ __launch_bounds__(256) void k_agg(const float* __restrict__ hin, const float* __restrict__ emb,
                       const float4* __restrict__ em4, const int* __restrict__ rs,
                       const int* __restrict__ eid, const int* __restrict__ esrc,
                       const float* __restrict__ epsp, float* __restrict__ tout){
  int t = threadIdx.x;
  int w = t >> 6;
  int lane = t & 63;
  int half = lane >> 5;
  int l32 = lane & 31;
  int n = blockIdx.x*4 + w;
  int d0 = l32*4;
  int rc0 = half*2, rc1 = rc0+1;
  float4 acc0 = {0.f,0.f,0.f,0.f}, acc1 = {0.f,0.f,0.f,0.f};
  int jb = rs[n], je = rs[n+1];
  for(int j=jb; j<je; j++){
    int e = eid[j], s = esrc[j];
    float4 ev = *(const float4*)&emb[(size_t)e*H + d0];
    float4 m  = em4[e];
    float m0 = half ? m.z : m.x;
    float m1 = half ? m.w : m.y;
    if(FIRST){
      float4 xv = *(const float4*)&hin[(size_t)s*H + d0];
      float gx = gelu_f(xv.x+ev.x);
      float gy = gelu_f(xv.y+ev.y);
      float gz = gelu_f(xv.z+ev.z);
      float gw = gelu_f(xv.w+ev.w);
      acc0.x += gx*m0; acc0.y += gy*m0; acc0.z += gz*m0; acc0.w += gw*m0;
      acc1.x += gx*m1; acc1.y += gy*m1; acc1.z += gz*m1; acc1.w += gw*m1;
    } else {
      float4 h0 = *(const float4*)&hin[((size_t)rc0*NN + s)*H + d0];
      float4 h1 = *(const float4*)&hin[((size_t)rc1*NN + s)*H + d0];
      acc0.x += gelu_f(h0.x+ev.x)*m0;
      acc0.y += gelu_f(h0.y+ev.y)*m0;
      acc0.z += gelu_f(h0.z+ev.z)*m0;
      acc0.w += gelu_f(h0.w+ev.w)*m0;
      acc1.x += gelu_f(h1.x+ev.x)*m1;
      acc1.y += gelu_f(h1.y+ev.y)*m1;
      acc1.z += gelu_f(h1.z+ev.z)*m1;
      acc1.w += gelu_f(h1.w+ev.w)*m1;
    }
  }
  float e1 = 1.0f + epsp[0];
  {
    const float* hb = FIRST ? (hin + (size_t)n*H) : (hin + ((size_t)rc0*NN + n)*H);
    float4 hv = *(const float4*)&hb[d0];
    float4 o;
    o.x = e1*hv.x + acc0.x; o.y = e1*hv.y + acc0.y;
    o.z = e1*hv.z + acc0.z; o.w = e1*hv.w + acc0.w;
    *(float4*)&tout[((size_t)rc0*NN + n)*H + d0] = o;
  }
  {
    const float* hb = FIRST ? (hin + (size_t)n*H) : (hin + ((size_t)rc1*NN + n)*H);
    float4 hv = *(const float4*)&hb[d0];
    float4 o;
    o.x = e1*hv.x + acc1.x; o.y = e1*hv.y + acc1.y;
    o.z = e1*hv.z + acc1.z; o.w = e1*hv.w + acc1.w;
    *(float4*)&tout[((size_t)rc1*NN + n)*H + d0] = o;
  }
}

// ---------- conv: h = gelu(gelu(t@W1+b1)@W2+b2); A/u in LDS, W1/W2 from global
__global__ __launch_bounds__(256) void k_conv(const float* __restrict__ T, const float* __restrict__ W1,
                        const float* __restrict__ b1, const float* __restrict__ W2,
                        const float* __restrict__ b2, float* __restrict__ Ho, int nrows){
  __shared__ float Al[128*LDA];   // 65 KB -> 2 blocks/CU
  int t = threadIdx.x;
  int rowbase = blockIdx.x*128;
  {
    #pragma unroll
    for(int i=0;i<16;i++){
      int idx = t + i*256;
      int r = idx >> 5, c4 = idx & 31;
      int gr = rowbase + r;
      float4 v = {0.f,0.f,0.f,0.f};
      if(gr < nrows) v = *(const float4*)&T[(size_t)gr*H + c4*4];
      *(float4*)&Al[r*LDA + c4*4] = v;
    }
  }
  __syncthreads();
  int tx = t & 15, ty = t >> 4;
  int c0 = tx*4, c1 = c0 + 64;
  int r0 = ty*4, r1 = r0 + 64;
  float acc[2][2][4][4] = {};
  #pragma unroll 2
  for(int k=0;k<H;k+=4){
    float4 wA[4], wB[4];
    #pragma unroll
    for(int kk=0;kk<4;kk++){
      wA[kk] = *(const float4*)&W1[(k+kk)*H + c0];
      wB[kk] = *(const float4*)&W1[(k+kk)*H + c1];
    }
    float4 aA[4], aB[4];
    #pragma unroll
    for(int i=0;i<4;i++){
      aA[i] = *(const float4*)&Al[(r0+i)*LDA + k];
      aB[i] = *(const float4*)&Al[(r1+i)*LDA + k];
    }
    #pragma unroll
    for(int i=0;i<4;i++){
      fma4(acc[0][0][i], aA[i], wA);
      fma4(acc[0][1][i], aA[i], wB);
      fma4(acc[1][0][i], aB[i], wA);
      fma4(acc[1][1][i], aB[i], wB);
    }
  }
  float4 bv0 = *(const float4*)&b1[c0];
  float4 bv1 = *(const float4*)&b1[c1];
  __syncthreads();   // all GEMM1 reads of Al complete
  #pragma unroll
  for(int i=0;i<4;i++){
    float4 o;
    o.x=gelu_f(acc[0][0][i][0]+bv0.x); o.y=gelu_f(acc[0][0][i][1]+bv0.y);
    o.z=gelu_f(acc[0][0][i][2]+bv0.z); o.w=gelu_f(acc[0][0][i][3]+bv0.w);
    *(float4*)&Al[(r0+i)*LDA + c0] = o;
    o.x=gelu_f(acc[0][1][i][0]+bv1.x); o.y=gelu_f(acc[0][1][i][1]+bv1.y);
    o.z=gelu_f(acc[0][1][i][2]+bv1.z); o.w=gelu_f(acc[0][1][i][3]+bv1.w);
    *(float4*)&Al[(r0+i)*LDA + c1] = o;
    o.x=gelu_f(acc[1][0][i][0]+bv0.x); o.y=gelu_f(acc[1][0][i][1]+bv0.y);
    o.z=gelu_f(acc[1][0][i][2]+bv0.z); o.w=gelu_f(acc[1][0][i][3]+bv0.w);
    *(float4*)&Al[(r1+i)*LDA + c0] = o;
    o.x=gelu_f(acc[1][1][i][0]+bv1.x); o.y=gelu_f(acc[1][1][i][1]+bv1.y);
    o.z=gelu_f(acc[1][1][i][2]+bv1.z); o.w=gelu_f(acc[1][1][i][3]+bv1.w);
    *(float4*)&Al[(r1+i)*LDA + c1] = o;
  }
  __syncthreads();
  float acc2[2][2][4][4] = {};
  #pragma unroll 2
  for(int k=0;k<H;k+=4){
    float4 wA[4], wB[4];
    #pragma unroll
    for(int kk=0;kk<4;kk++){
      wA[kk] = *(const float4*)&W2[(k+kk)*H + c0];
      wB[kk] = *(const float4*)&W2[(k+kk)*H + c1];
    }
    float4 aA[4], aB[4];
    #pragma unroll
    for(int i=0;i<4;i++){
      aA[i] = *(const float4*)&Al[(r0+i)*LDA + k];
      aB[i] = *(const float4*)&Al[(r1+i)*LDA + k];
    }
    #pragma unroll
    for(int i=0;i<4;i++){
      fma4(acc2[0][0][i], aA[i], wA);
      fma4(acc2[0][1][i], aA[i], wB);
      fma4(acc2[1][0][i], aB[i], wA);
      fma4(acc2[1][1][i], aB[i], wB);
    }
  }
  float4 c2v0 = *(const float4*)&b2[c0];
  float4 c2v1 = *(const float4*)&b2[c1];
  #pragma unroll
  for(int i=0;i<4;i++){
    int gr0 = rowbase + r0 + i, gr1 = rowbase + r1 + i;
    float4 o;
    if(gr0 < nrows){
      o.x=gelu_f(acc2[0][0][i][0]+c2v0.x); o.y=gelu_f(acc2[0][0][i][1]+c2v0.y);
      o.z=gelu_f(acc2[0][0][i][2]+c2v0.z); o.w=gelu_f(acc2[0][0][i][3]+c2v0.w);
      *(float4*)&Ho[(size_t)gr0*H + c0] = o;
      o.x=gelu_f(acc2[0][1][i][0]+c2v1.x); o.y=gelu_f(acc2[0][1][i][1]+c2v1.y);
      o.z=gelu_f(acc2[0][1][i][2]+c2v1.z); o.w=gelu_f(acc2[0][1][i][3]+c2v1.w);
      *(float4*)&Ho[(size_t)gr0*H + c1] = o;
    }
    if(gr1 < nrows){
      o.x=gelu_f(acc2[1][0][i][0]+c2v0.x); o.y=gelu_f(acc2[1][0][i][1]+c2v0.y);
      o.z=gelu_f(acc2[1][0][i][2]+c2v0.z); o.w=gelu_f(acc2[1][0][i][3]+c2v0.w);
      *(float4*)&Ho[(size_t)gr1*H + c0] = o;
      o.x=gelu_f(acc2[1][1][i][0]+c2v1.x); o.y=gelu_f(acc2[1][1][i][1]+c2v1.y);
      o.z=gelu_f(acc2[1][1][i][2]+c2v1.z); o.w=gelu_f(acc2[1][1][i][3]+c2v1.w);
      *(float4*)&Ho[(size_t)gr1*H + c1] = o;
    }
  }
}

// ---------- final MLP: y = gelu(h@W1+b1)@W2+b2; A/u in LDS, W from global
__global__ __launch_bounds__(256) void k_mlp(const float* __restrict__ Hf, const float* __restrict__ W1,
     const float* __restrict__ b1, const float* __restrict__ W2, const float* __restrict__ b2,
     float* __restrict__ y, int nrows){
  __shared__ float Al[128*LDA];
  int t = threadIdx.x;
  int rowbase = blockIdx.x*128;
  {
    #pragma unroll
    for(int i=0;i<16;i++){
      int idx = t + i*256;
      int r = idx >> 5, c4 = idx & 31;
      int gr = rowbase + r;
      float4 v = {0.f,0.f,0.f,0.f};
      if(gr < nrows) v = *(const float4*)&Hf[(size_t)gr*H + c4*4];
      *(float4*)&Al[r*LDA + c4*4] = v;
    }
  }
  __syncthreads();
  int tx = t & 15, ty = t >> 4;
  int c0 = tx*4, c1 = c0 + 64;
  int r0 = ty*4, r1 = r0 + 64;
  float acc[2][2][4][4] = {};
  #pragma unroll 2
  for(int k=0;k<H;k+=4){
    float4 wA[4], wB[4];
    #pragma unroll
    for(int kk=0;kk<4;kk++){
      wA[kk] = *(const float4*)&W1[(k+kk)*H + c0];
      wB[kk] = *(const float4*)&W1[(k+kk)*H + c1];
    }
    float4 aA[4], aB[4];
    #pragma unroll
    for(int i=0;i<4;i++){
      aA[i] = *(const float4*)&Al[(r0+i)*LDA + k];
      aB[i] = *(const float4*)&Al[(r1+i)*LDA + k];
    }
    #pragma unroll
    for(int i=0;i<4;i++){
      fma4(acc[0][0][i], aA[i], wA);
      fma4(acc[0][1][i], aA[i], wB);
      fma4(acc[1][0][i], aB[i], wA);
      fma4(acc[1][1][i], aB[i], wB);
    }
  }
  float4 bv0 = *(const float4*)&b1[c0];
  float4 bv1 = *(const float4*)&b1[c1];
  __syncthreads();
  #pragma unroll
  for(int i=0;i<4;i++){
    float4 o;
    o.x=gelu_f(acc[0][0][i][0]+bv0.x); o.y=gelu_f(acc[0][0][i][1]+bv0.y);
    o.z=gelu_f(acc[0][0][i][2]+bv0.z); o.w=gelu_f(acc[0][0][i][3]+bv0.w);
    *(float4*)&Al[(r0+i)*LDA + c0] = o;
    o.x=gelu_f(acc[0][1][i][0]+bv1.x); o.y=gelu_f(acc[0][1][i][1]+bv1.y);
    o.z=gelu_f(acc[0][1][i][2]+bv1.z); o.w=gelu_f(acc[0][1][i][3]+bv1.w);
    *(float4*)&Al[(r0+i)*LDA + c1] = o;
    o.x=gelu_f(acc[1][0][i][0]+bv0.x); o.y=gelu_f(acc[1][0][i][1]+bv0.y);
    o.z=gelu_f(acc[1][0][i][2]+bv0.z); o.w=gelu_f(acc[1][0][i][3]+bv0.w);
    *(float4*)&Al[(r1+i)*LDA + c0] = o;
    o.x=gelu_f(acc[1][1][i][0]+bv1.x); o.y=gelu_f(acc[1][1][i][1]+bv1.y);
    o.z=gelu_f(acc[1][1][i][2]+bv1.z); o.w=gelu_f(acc[1][1][i][3]+bv1.w);
    *(float4*)&Al[(r1+i)*LDA + c1] = o;
  }
  __syncthreads();
  // GEMM2: 128 rows x 64 cols; thread = 8 rows x 4 cols
  int tx2 = t & 15, ty2 = t >> 4;
  int c2 = tx2*4;
  int rr = ty2*8;
  float a2[8][4] = {};
  #pragma unroll 2
  for(int k=0;k<H;k+=4){
    float4 wv[4];
    #pragma unroll
    for(int kk=0;kk<4;kk++) wv[kk] = *(const float4*)&W2[(k+kk)*OUTF + c2];
    #pragma unroll
    for(int i=0;i<8;i++){
      float4 a = *(const float4*)&Al[(rr+i)*LDA + k];
      fma4(a2[i], a, wv);
    }
  }
  float4 b2v = *(const float4*)&b2[c2];
  #pragma unroll
  for(int i=0;i<8;i++){
    int gr = rowbase + rr + i;
    if(gr < nrows){
      float4 o;
      o.x = a2[i][0]+b2v.x; o.y = a2[i][1]+b2v.y;
      o.z = a2[i][2]+b2v.z; o.w = a2[i][3]+b2v.w;
      *(float4*)&y[(size_t)gr*OUTF + c2] = o;
    }
  }
}

// ---------- deterministic masked segment mean
__global__ __launch_bounds__(64) void k_pool(const float* __restrict__ y, const float* __restrict__ nm,
                       const int* __restrict__ gs, float* __restrict__ out){
  int seg = blockIdx.x;
  int rc = seg / NG;
  int g  = seg - rc*NG;
  int c  = threadIdx.x;
  int nb = gs[g], ne = gs[g+1];
  float num = 0.f, den = 0.f;
  for(int n=nb; n<ne; n++){
    float w = nm[rc*NN + n];
    num += y[((size_t)rc*NN + n)*OUTF + c] * w;
    den += w;
  }
  out[seg*OUTF + c] = num / fmaxf(den, 1e-12f);
}

extern "C" void kernel_launch(void* const* d_in, const int* in_sizes, int n_in,
                              void* d_out, int out_size, void* d_ws, size_t ws_size,
                              hipStream_t stream){
  const float* x         = (const float*)d_in[0];
  const float* edge_attr = (const float*)d_in[1];
  const float* node_mask = (const float*)d_in[2];
  const float* bond_W    = (const float*)d_in[3];
  const float* bond_b    = (const float*)d_in[4];
  const float* epsv      = (const float*)d_in[5];
  const float* conv_W1   = (const float*)d_in[6];
  const float* conv_b1   = (const float*)d_in[7];
  const float* conv_W2   = (const float*)d_in[8];
  const float* conv_b2   = (const float*)d_in[9];
  const float* mlp_W1    = (const float*)d_in[10];
  const float* mlp_b1    = (const float*)d_in[11];
  const float* mlp_W2    = (const float*)d_in[12];
  const float* mlp_b2    = (const float*)d_in[13];
  const int*   eidx      = (const int*)d_in[14];
  const int*   batch     = (const int*)d_in[15];
  const int* srcp = eidx;
  const int* dstp = eidx + EE;

  char* p = (char*)d_ws;
  auto alloc = [&](size_t bytes)->char*{
    char* r = p; p += (bytes + 255) & ~size_t(255); return r;
  };
  float*  h    = (float*) alloc((size_t)RCN*NN*H*4);
  float*  tbuf = (float*) alloc((size_t)RCN*NN*H*4);
  float*  emb  = (float*) alloc((size_t)EE*H*4);
  float4* em4  = (float4*)alloc((size_t)EE*16);
  float*  y    = (float*) alloc((size_t)RCN*NN*OUTF*4);
  int*    cnt  = (int*)   alloc((size_t)NN*4);
  int*    rs   = (int*)   alloc((size_t)(NN+1)*4);
  int*    cur  = (int*)   alloc((size_t)NN*4);
  int*    eid  = (int*)   alloc((size_t)EE*4);
  int*    esrc = (int*)   alloc((size_t)EE*4);
  int*    gs   = (int*)   alloc((size_t)(NG+1)*4);
  if((size_t)(p - (char*)d_ws) > ws_size) return;

  hipMemsetAsync(cnt, 0, (size_t)NN*4, stream);

  k_edge_mask<<<(EE+255)/256, 256, 0, stream>>>(srcp, dstp, node_mask, em4);
  k_hist     <<<(EE+255)/256, 256, 0, stream>>>(dstp, cnt);
  k_scan     <<<1, 1024, 0, stream>>>(cnt, rs, cur);
  k_fill     <<<(EE+255)/256, 256, 0, stream>>>(dstp, cur, eid);
  k_sortcsr  <<<(NN+255)/256, 256, 0, stream>>>(rs, eid, srcp, esrc);
  k_gbounds  <<<1, 128, 0, stream>>>(batch, gs);

  const int NROWS = RCN*NN;
  for(int l=0; l<3; l++){
    k_emb<<<EE/128, 256, 0, stream>>>(edge_attr, bond_W + (size_t)l*H*H, bond_b + l*H, emb);
    if(l == 0)
      k_agg<true ><<<NN/4, 256, 0, stream>>>(x, emb, em4, rs, eid, esrc, epsv + l, tbuf);
    else
      k_agg<false><<<NN/4, 256, 0, stream>>>(h, emb, em4, rs, eid, esrc, epsv + l, tbuf);
    k_conv<<<(NROWS+127)/128, 256, 0, stream>>>(tbuf, conv_W1 + (size_t)l*H*H, conv_b1 + l*H,
                                                conv_W2 + (size_t)l*H*H, conv_b2 + l*H, h, NROWS);
  }
  k_mlp<<<(NROWS+127)/128, 256, 0, stream>>>(h, mlp_W1, mlp_b1, mlp_W2, mlp_b2, y, NROWS);
  k_pool<<<DSEG, 64, 0, stream>>>(y, node_mask, gs, (float*)d_out);
}

// Round 5
// 970.568 us; speedup vs baseline: 1.2727x; 1.2727x over previous
//
#include <hip/hip_runtime.h>

constexpr int H    = 128;
constexpr int NN   = 10000;
constexpr int EE   = 160000;
constexpr int RCN  = 4;      // R*C
constexpr int NG   = 64;     // graphs per replica
constexpr int OUTF = 64;
constexpr int DSEG = 256;    // RCN*NG

__device__ __forceinline__ float gelu_f(float x){
  return 0.5f*x*(1.0f + erff(x*0.70710678118654752440f));
}

__device__ __forceinline__ void fma4(float acc[4], float4 a, const float4 w[4]){
  acc[0] += a.x*w[0].x + a.y*w[1].x + a.z*w[2].x + a.w*w[3].x;
  acc[1] += a.x*w[0].y + a.y*w[1].y + a.z*w[2].y + a.w*w[3].y;
  acc[2] += a.x*w[0].z + a.y*w[1].z + a.z*w[2].z + a.w*w[3].z;
  acc[3] += a.x*w[0].w + a.y*w[1].w + a.z*w[2].w + a.w*w[3].w;
}

// ---------- edge mask
__global__ void k_edge_mask(const int* __restrict__ src, const int* __restrict__ dst,
                            const float* __restrict__ nm, float4* __restrict__ em4){
  int e = blockIdx.x*256 + threadIdx.x;
  if(e >= EE) return;
  int s = src[e], d = dst[e];
  float4 m;
  m.x = nm[0*NN+s]*nm[0*NN+d];
  m.y = nm[1*NN+s]*nm[1*NN+d];
  m.z = nm[2*NN+s]*nm[2*NN+d];
  m.w = nm[3*NN+s]*nm[3*NN+d];
  em4[e] = m;
}

// ---------- CSR build
__global__ void k_hist(const int* __restrict__ dst, int* __restrict__ cnt){
  int e = blockIdx.x*256 + threadIdx.x;
  if(e < EE) atomicAdd(&cnt[dst[e]], 1);
}

__global__ __launch_bounds__(1024) void k_scan(const int* __restrict__ cnt,
                                               int* __restrict__ rs, int* __restrict__ cur){
  __shared__ int part[1024];
  int t = threadIdx.x;
  const int CH = 10;
  int base = t*CH;
  int s = 0;
  #pragma unroll
  for(int j=0;j<CH;j++){ int i = base+j; if(i<NN) s += cnt[i]; }
  part[t] = s;
  __syncthreads();
  for(int off=1; off<1024; off<<=1){
    int v = (t>=off) ? part[t-off] : 0;
    __syncthreads();
    part[t] += v;
    __syncthreads();
  }
  int run = (t==0) ? 0 : part[t-1];
  #pragma unroll
  for(int j=0;j<CH;j++){
    int i = base+j;
    if(i<NN){ rs[i] = run; cur[i] = run; run += cnt[i]; }
  }
  if(t == 1023) rs[NN] = part[1023];
}

__global__ void k_fill(const int* __restrict__ dst,
                       int* __restrict__ cur, int* __restrict__ eid){
  int e = blockIdx.x*256 + threadIdx.x;
  if(e >= EE) return;
  int p = atomicAdd(&cur[dst[e]], 1);
  eid[p] = e;
}

__global__ void k_sortcsr(const int* __restrict__ rs, int* __restrict__ eid,
                          const int* __restrict__ src, int* __restrict__ esrc){
  int n = blockIdx.x*256 + threadIdx.x;
  if(n >= NN) return;
  int jb = rs[n], je = rs[n+1];
  for(int j=jb+1; j<je; j++){
    int v = eid[j];
    int k = j-1;
    while(k >= jb && eid[k] > v){ eid[k+1] = eid[k]; k--; }
    eid[k+1] = v;
  }
  for(int j=jb; j<je; j++) esrc[j] = src[eid[j]];
}

__global__ void k_gbounds(const int* __restrict__ batch, int* __restrict__ gs){
  int g = threadIdx.x;
  if(g > NG) return;
  if(g == NG){ gs[NG] = NN; return; }
  int lo = 0, hi = NN;
  while(lo < hi){
    int mid = (lo+hi)>>1;
    if(batch[mid] < g) lo = mid+1; else hi = mid;
  }
  gs[g] = lo;
}

// ---------- panel GEMM: C = act(A[nrows x 128] @ W[128 x BN] + b), tile 128 x BN
// K in 4 panels of 32, double-buffered LDS, issue-early/write-late staging.
template<int BN, bool GELU>
__global__ __launch_bounds__(256, 2) void k_gemm(const float* __restrict__ A,
    const float* __restrict__ W, const float* __restrict__ bias,
    float* __restrict__ C, int nrows){
  constexpr int LDAS = 36;       // 4*36=144 B row stride: row-groups of 4 -> bank shift 16 (2-way, free)
  constexpr int CN = BN/64;      // column register-tile count (2 for BN=128, 1 for BN=64)
  __shared__ float As[2][128*LDAS];   // 18432 B each
  __shared__ float Ws[2][32*BN];      // 16 KB (BN=128) / 8 KB (BN=64) each
  int t = threadIdx.x;
  int rowbase = blockIdx.x*128;

  float4 ra[4];        // A staging regs: 128 rows x 32 k = 1024 float4 / 256 thr
  float4 rw[BN/32];    // W staging regs: 32*BN floats / 256 thr / 4

  auto loadA = [&](int p){
    #pragma unroll
    for(int i=0;i<4;i++){
      int idx = i*256 + t;
      int r = idx>>3, c4 = idx&7;
      int gr = rowbase + r;
      if(gr < nrows) ra[i] = *(const float4*)&A[(size_t)gr*H + p*32 + c4*4];
      else           ra[i] = make_float4(0.f,0.f,0.f,0.f);
    }
  };
  auto loadW = [&](int p){
    #pragma unroll
    for(int i=0;i<BN/32;i++)
      rw[i] = *(const float4*)&W[p*32*BN + (i*256+t)*4];
  };
  auto writeA = [&](int b){
    #pragma unroll
    for(int i=0;i<4;i++){
      int idx = i*256 + t;
      int r = idx>>3, c4 = idx&7;
      *(float4*)&As[b][r*LDAS + c4*4] = ra[i];
    }
  };
  auto writeW = [&](int b){
    #pragma unroll
    for(int i=0;i<BN/32;i++)
      *(float4*)&Ws[b][(i*256+t)*4] = rw[i];
  };

  int tx = t & 15, ty = t >> 4;
  int c0 = tx*4;
  int r0 = ty*4, r1 = r0 + 64;

  float acc[2][CN][4][4] = {};

  loadA(0); loadW(0);
  writeA(0); writeW(0);
  __syncthreads();
  for(int p=0;p<4;p++){
    int b = p & 1;
    if(p < 3){ loadA(p+1); loadW(p+1); }   // in flight during compute
    #pragma unroll 2
    for(int k=0;k<32;k+=4){
      float4 wv[CN][4];
      #pragma unroll
      for(int kk=0;kk<4;kk++){
        wv[0][kk] = *(const float4*)&Ws[b][(k+kk)*BN + c0];
        if constexpr(CN == 2)
          wv[1][kk] = *(const float4*)&Ws[b][(k+kk)*BN + c0 + 64];
      }
      float4 av[2][4];
      #pragma unroll
      for(int i=0;i<4;i++){
        av[0][i] = *(const float4*)&As[b][(r0+i)*LDAS + k];
        av[1][i] = *(const float4*)&As[b][(r1+i)*LDAS + k];
      }
      #pragma unroll
      for(int i=0;i<4;i++){
        #pragma unroll
        for(int ri=0;ri<2;ri++){
          fma4(acc[ri][0][i], av[ri][i], wv[0]);
          if constexpr(CN == 2) fma4(acc[ri][1][i], av[ri][i], wv[1]);
        }
      }
    }
    if(p < 3){ writeA(b^1); writeW(b^1); }  // vmcnt wait happens here
    __syncthreads();
  }

  float4 bv[CN];
  bv[0] = *(const float4*)&bias[c0];
  if constexpr(CN == 2) bv[1] = *(const float4*)&bias[c0+64];
  #pragma unroll
  for(int ri=0;ri<2;ri++){
    #pragma unroll
    for(int i=0;i<4;i++){
      int gr = rowbase + (ri ? r1 : r0) + i;
      if(gr >= nrows) continue;
      #pragma unroll
      for(int cj=0;cj<CN;cj++){
        float bx[4] = { ((const float*)&bv[cj])[0], ((const float*)&bv[cj])[1],
                        ((const float*)&bv[cj])[2], ((const float*)&bv[cj])[3] };
        float4 o;
        if constexpr(GELU){
          o.x = gelu_f(acc[ri][cj][i][0]+bx[0]);
          o.y = gelu_f(acc[ri][cj][i][1]+bx[1]);
          o.z = gelu_f(acc[ri][cj][i][2]+bx[2]);
          o.w = gelu_f(acc[ri][cj][i][3]+bx[3]);
        } else {
          o.x = acc[ri][cj][i][0]+bx[0];
          o.y = acc[ri][cj][i][1]+bx[1];
          o.z = acc[ri][cj][i][2]+bx[2];
          o.w = acc[ri][cj][i][3]+bx[3];
        }
        *(float4*)&C[(size_t)gr*BN + c0 + cj*64] = o;
      }
    }
  }
}

// ---------- aggregation: one wave per node, rc-pair per half-wave, 1-deep prefetch
template<bool FIRST>
__global__ __launch_bounds__(256) void k_agg(const float* __restrict__ hin, const float* __restrict__ emb,
                       const float4* __restrict__ em4, const int* __restrict__ rs,
                       const int* __restrict__ eid, const int* __restrict__ esrc,
                       const float* __restrict__ epsp, float* __restrict__ tout){
  int t = threadIdx.x;
  int w = t >> 6;
  int lane = t & 63;
  int half = lane >> 5;
  int l32 = lane & 31;
  int n = blockIdx.x*4 + w;
  int d0 = l32*4;
  int rc0 = half*2, rc1 = rc0+1;
  float4 acc0 = {0.f,0.f,0.f,0.f}, acc1 = {0.f,0.f,0.f,0.f};
  int jb = rs[n], je = rs[n+1];
  if(jb < je){
    int e = eid[jb], s = esrc[jb];
    float4 ev = *(const float4*)&emb[(size_t)e*H + d0];
    float4 m  = em4[e];
    float4 h0, h1;
    if(FIRST){
      h0 = *(const float4*)&hin[(size_t)s*H + d0];
      h1 = h0;
    } else {
      h0 = *(const float4*)&hin[((size_t)rc0*NN + s)*H + d0];
      h1 = *(const float4*)&hin[((size_t)rc1*NN + s)*H + d0];
    }
    for(int j=jb; j<je; j++){
      float4 ev_n = {0,0,0,0}, m_n = {0,0,0,0}, h0_n = {0,0,0,0}, h1_n = {0,0,0,0};
      if(j+1 < je){   // wave-uniform branch; prefetch next edge
        int e2 = eid[j+1], s2 = esrc[j+1];
        ev_n = *(const float4*)&emb[(size_t)e2*H + d0];
        m_n  = em4[e2];
        if(FIRST){
          h0_n = *(const float4*)&hin[(size_t)s2*H + d0];
          h1_n = h0_n;
        } else {
          h0_n = *(const float4*)&hin[((size_t)rc0*NN + s2)*H + d0];
          h1_n = *(const float4*)&hin[((size_t)rc1*NN + s2)*H + d0];
        }
      }
      float m0 = half ? m.z : m.x;
      float m1 = half ? m.w : m.y;
      if(FIRST){
        float gx = gelu_f(h0.x+ev.x);
        float gy = gelu_f(h0.y+ev.y);
        float gz = gelu_f(h0.z+ev.z);
        float gw = gelu_f(h0.w+ev.w);
        acc0.x += gx*m0; acc0.y += gy*m0; acc0.z += gz*m0; acc0.w += gw*m0;
        acc1.x += gx*m1; acc1.y += gy*m1; acc1.z += gz*m1; acc1.w += gw*m1;
      } else {
        acc0.x += gelu_f(h0.x+ev.x)*m0;
        acc0.y += gelu_f(h0.y+ev.y)*m0;
        acc0.z += gelu_f(h0.z+ev.z)*m0;
        acc0.w += gelu_f(h0.w+ev.w)*m0;
        acc1.x += gelu_f(h1.x+ev.x)*m1;
        acc1.y += gelu_f(h1.y+ev.y)*m1;
        acc1.z += gelu_f(h1.z+ev.z)*m1;
        acc1.w += gelu_f(h1.w+ev.w)*m1;
      }
      ev = ev_n; m = m_n; h0 = h0_n; h1 = h1_n;
    }
  }
  float e1 = 1.0f + epsp[0];
  {
    const float* hb = FIRST ? (hin + (size_t)n*H) : (hin + ((size_t)rc0*NN + n)*H);
    float4 hv = *(const float4*)&hb[d0];
    float4 o;
    o.x = e1*hv.x + acc0.x; o.y = e1*hv.y + acc0.y;
    o.z = e1*hv.z + acc0.z; o.w = e1*hv.w + acc0.w;
    *(float4*)&tout[((size_t)rc0*NN + n)*H + d0] = o;
  }
  {
    const float* hb = FIRST ? (hin + (size_t)n*H) : (hin + ((size_t)rc1*NN + n)*H);
    float4 hv = *(const float4*)&hb[d0];
    float4 o;
    o.x = e1*hv.x + acc1.x; o.y = e1*hv.y + acc1.y;
    o.z = e1*hv.z + acc1.z; o.w = e1*hv.w + acc1.w;
    *(float4*)&tout[((size_t)rc1*NN + n)*H + d0] = o;
  }
}

// ---------- deterministic masked segment mean
__global__ __launch_bounds__(64) void k_pool(const float* __restrict__ y, const float* __restrict__ nm,
                       const int* __restrict__ gs, float* __restrict__ out){
  int seg = blockIdx.x;
  int rc = seg / NG;
  int g  = seg - rc*NG;
  int c  = threadIdx.x;
  int nb = gs[g], ne = gs[g+1];
  float num = 0.f, den = 0.f;
  for(int n=nb; n<ne; n++){
    float w = nm[rc*NN + n];
    num += y[((size_t)rc*NN + n)*OUTF + c] * w;
    den += w;
  }
  out[seg*OUTF + c] = num / fmaxf(den, 1e-12f);
}

extern "C" void kernel_launch(void* const* d_in, const int* in_sizes, int n_in,
                              void* d_out, int out_size, void* d_ws, size_t ws_size,
                              hipStream_t stream){
  const float* x         = (const float*)d_in[0];
  const float* edge_attr = (const float*)d_in[1];
  const float* node_mask = (const float*)d_in[2];
  const float* bond_W    = (const float*)d_in[3];
  const float* bond_b    = (const float*)d_in[4];
  const float* epsv      = (const float*)d_in[5];
  const float* conv_W1   = (const float*)d_in[6];
  const float* conv_b1   = (const float*)d_in[7];
  const float* conv_W2   = (const float*)d_in[8];
  const float* conv_b2   = (const float*)d_in[9];
  const float* mlp_W1    = (const float*)d_in[10];
  const float* mlp_b1    = (const float*)d_in[11];
  const float* mlp_W2    = (const float*)d_in[12];
  const float* mlp_b2    = (const float*)d_in[13];
  const int*   eidx      = (const int*)d_in[14];
  const int*   batch     = (const int*)d_in[15];
  const int* srcp = eidx;
  const int* dstp = eidx + EE;

  char* p = (char*)d_ws;
  auto alloc = [&](size_t bytes)->char*{
    char* r = p; p += (bytes + 255) & ~size_t(255); return r;
  };
  float*  h    = (float*) alloc((size_t)RCN*NN*H*4);
  float*  tbuf = (float*) alloc((size_t)RCN*NN*H*4);
  float*  u    = (float*) alloc((size_t)RCN*NN*H*4);
  float*  emb  = (float*) alloc((size_t)EE*H*4);
  float4* em4  = (float4*)alloc((size_t)EE*16);
  float*  y    = (float*) alloc((size_t)RCN*NN*OUTF*4);
  int*    cnt  = (int*)   alloc((size_t)NN*4);
  int*    rs   = (int*)   alloc((size_t)(NN+1)*4);
  int*    cur  = (int*)   alloc((size_t)NN*4);
  int*    eid  = (int*)   alloc((size_t)EE*4);
  int*    esrc = (int*)   alloc((size_t)EE*4);
  int*    gs   = (int*)   alloc((size_t)(NG+1)*4);
  if((size_t)(p - (char*)d_ws) > ws_size) return;

  hipMemsetAsync(cnt, 0, (size_t)NN*4, stream);

  k_edge_mask<<<(EE+255)/256, 256, 0, stream>>>(srcp, dstp, node_mask, em4);
  k_hist     <<<(EE+255)/256, 256, 0, stream>>>(dstp, cnt);
  k_scan     <<<1, 1024, 0, stream>>>(cnt, rs, cur);
  k_fill     <<<(EE+255)/256, 256, 0, stream>>>(dstp, cur, eid);
  k_sortcsr  <<<(NN+255)/256, 256, 0, stream>>>(rs, eid, srcp, esrc);
  k_gbounds  <<<1, 128, 0, stream>>>(batch, gs);

  const int NROWS = RCN*NN;
  const int GB_E = EE/128;             // 1250
  const int GB_N = (NROWS+127)/128;    // 313
  for(int l=0; l<3; l++){
    k_gemm<128,false><<<GB_E, 256, 0, stream>>>(edge_attr, bond_W + (size_t)l*H*H,
                                                bond_b + l*H, emb, EE);
    if(l == 0)
      k_agg<true ><<<NN/4, 256, 0, stream>>>(x, emb, em4, rs, eid, esrc, epsv + l, tbuf);
    else
      k_agg<false><<<NN/4, 256, 0, stream>>>(h, emb, em4, rs, eid, esrc, epsv + l, tbuf);
    k_gemm<128,true><<<GB_N, 256, 0, stream>>>(tbuf, conv_W1 + (size_t)l*H*H,
                                               conv_b1 + l*H, u, NROWS);
    k_gemm<128,true><<<GB_N, 256, 0, stream>>>(u, conv_W2 + (size_t)l*H*H,
                                               conv_b2 + l*H, h, NROWS);
  }
  k_gemm<128,true><<<GB_N, 256, 0, stream>>>(h, mlp_W1, mlp_b1, u, NROWS);
  k_gemm<64,false><<<GB_N, 256, 0, stream>>>(u, mlp_W2, mlp_b2, y, NROWS);
  k_pool<<<DSEG, 64, 0, stream>>>(y, node_mask, gs, (float*)d_out);
}

// Round 6
// 895.832 us; speedup vs baseline: 1.3788x; 1.0834x over previous
//
#include <hip/hip_runtime.h>

constexpr int H    = 128;
constexpr int NN   = 10000;
constexpr int EE   = 160000;
constexpr int RCN  = 4;      // R*C
constexpr int NG   = 64;     // graphs per replica
constexpr int OUTF = 64;
constexpr int DSEG = 256;    // RCN*NG

using short8 = __attribute__((ext_vector_type(8))) short;
using f32x4  = __attribute__((ext_vector_type(4))) float;

__device__ __forceinline__ float gelu_f(float x){
  return 0.5f*x*(1.0f + erff(x*0.70710678118654752440f));
}

// ---------- edge mask
__global__ void k_edge_mask(const int* __restrict__ src, const int* __restrict__ dst,
                            const float* __restrict__ nm, float4* __restrict__ em4){
  int e = blockIdx.x*256 + threadIdx.x;
  if(e >= EE) return;
  int s = src[e], d = dst[e];
  float4 m;
  m.x = nm[0*NN+s]*nm[0*NN+d];
  m.y = nm[1*NN+s]*nm[1*NN+d];
  m.z = nm[2*NN+s]*nm[2*NN+d];
  m.w = nm[3*NN+s]*nm[3*NN+d];
  em4[e] = m;
}

// ---------- CSR build
__global__ void k_hist(const int* __restrict__ dst, int* __restrict__ cnt){
  int e = blockIdx.x*256 + threadIdx.x;
  if(e < EE) atomicAdd(&cnt[dst[e]], 1);
}

__global__ __launch_bounds__(1024) void k_scan(const int* __restrict__ cnt,
                                               int* __restrict__ rs, int* __restrict__ cur){
  __shared__ int part[1024];
  int t = threadIdx.x;
  const int CH = 10;
  int base = t*CH;
  int s = 0;
  #pragma unroll
  for(int j=0;j<CH;j++){ int i = base+j; if(i<NN) s += cnt[i]; }
  part[t] = s;
  __syncthreads();
  for(int off=1; off<1024; off<<=1){
    int v = (t>=off) ? part[t-off] : 0;
    __syncthreads();
    part[t] += v;
    __syncthreads();
  }
  int run = (t==0) ? 0 : part[t-1];
  #pragma unroll
  for(int j=0;j<CH;j++){
    int i = base+j;
    if(i<NN){ rs[i] = run; cur[i] = run; run += cnt[i]; }
  }
  if(t == 1023) rs[NN] = part[1023];
}

__global__ void k_fill(const int* __restrict__ dst,
                       int* __restrict__ cur, int* __restrict__ eid){
  int e = blockIdx.x*256 + threadIdx.x;
  if(e >= EE) return;
  int p = atomicAdd(&cur[dst[e]], 1);
  eid[p] = e;
}

__global__ void k_sortcsr(const int* __restrict__ rs, int* __restrict__ eid,
                          const int* __restrict__ src, int* __restrict__ esrc){
  int n = blockIdx.x*256 + threadIdx.x;
  if(n >= NN) return;
  int jb = rs[n], je = rs[n+1];
  for(int j=jb+1; j<je; j++){
    int v = eid[j];
    int k = j-1;
    while(k >= jb && eid[k] > v){ eid[k+1] = eid[k]; k--; }
    eid[k+1] = v;
  }
  for(int j=jb; j<je; j++) esrc[j] = src[eid[j]];
}

__global__ void k_gbounds(const int* __restrict__ batch, int* __restrict__ gs){
  int g = threadIdx.x;
  if(g > NG) return;
  if(g == NG){ gs[NG] = NN; return; }
  int lo = 0, hi = NN;
  while(lo < hi){
    int mid = (lo+hi)>>1;
    if(batch[mid] < g) lo = mid+1; else hi = mid;
  }
  gs[g] = lo;
}

// ---------- split W (fp32 -> 3x bf16, RNE) into MFMA B-fragment-linear layout
// B-frag for 16x16x32: lane = (n%16) + 16*kg, elem e: k = 16*(e>>2) + 4*kg + (e&3)
__global__ void k_splitW(const float* __restrict__ W, unsigned short* __restrict__ oh,
                         unsigned short* __restrict__ om, unsigned short* __restrict__ ol,
                         int nmat, int N){
  int tid = blockIdx.x*256 + threadIdx.x;
  int total = nmat*128*N;
  if(tid >= total) return;
  int mat = tid / (128*N);
  int rem = tid - mat*(128*N);
  int k = rem / N;
  int n = rem - k*N;
  int NF = N >> 4;
  int ks = k >> 5, kk = k & 31;
  int nf = n >> 4;
  int lane = (n & 15) + 16*((kk & 15) >> 2);
  int e = 4*(kk >> 4) + (kk & 3);
  size_t idx = (size_t)mat*128*N + ((size_t)(ks*NF + nf)*64 + lane)*8 + e;
  float x = W[tid];
  unsigned int u = __float_as_uint(x);
  unsigned int rh = u + 0x7FFF + ((u>>16)&1);
  unsigned short hh = (unsigned short)(rh>>16);
  float fh = __uint_as_float((unsigned int)hh << 16);
  float r1 = x - fh;
  unsigned int u1 = __float_as_uint(r1);
  unsigned int rm = u1 + 0x7FFF + ((u1>>16)&1);
  unsigned short mm = (unsigned short)(rm>>16);
  float fm = __uint_as_float((unsigned int)mm << 16);
  float r2 = r1 - fm;
  unsigned int u2 = __float_as_uint(r2);
  unsigned int rl = u2 + 0x7FFF + ((u2>>16)&1);
  unsigned short ll = (unsigned short)(rl>>16);
  oh[idx] = hh; om[idx] = mm; ol[idx] = ll;
}

// ---------- MFMA GEMM: C = act(A[nrows x 128] @ W[128 x N] + b), bf16x3 split (6 terms)
// 128-row tile per block, 4 waves, each wave: 32 rows x N cols.
template<int NF, bool GELU>
__global__ __launch_bounds__(256) void k_mgemm(const float* __restrict__ A,
    const unsigned short* __restrict__ Wh, const unsigned short* __restrict__ Wm,
    const unsigned short* __restrict__ Wl, const float* __restrict__ bias,
    float* __restrict__ C, int nrows){
  __shared__ float Al[128*132];   // 66 KB -> 2 blocks/CU
  int t = threadIdx.x;
  int rowbase = blockIdx.x*128;
  #pragma unroll
  for(int i=0;i<16;i++){
    int idx = i*256 + t;
    int r = idx >> 5, c4 = idx & 31;
    int gr = rowbase + r;
    float4 v = {0.f,0.f,0.f,0.f};
    if(gr < nrows) v = *(const float4*)&A[(size_t)gr*H + c4*4];
    *(float4*)&Al[r*132 + c4*4] = v;
  }
  __syncthreads();
  int w = t >> 6, lane = t & 63;
  int m15 = lane & 15, kg = lane >> 4;

  f32x4 acc[2][NF];
  #pragma unroll
  for(int mf=0;mf<2;mf++)
    #pragma unroll
    for(int nf=0;nf<NF;nf++) acc[mf][nf] = (f32x4){0.f,0.f,0.f,0.f};

  for(int ks=0;ks<4;ks++){
    short8 ah[2], am[2], alo[2];
    #pragma unroll
    for(int mf=0;mf<2;mf++){
      int row = w*32 + mf*16 + m15;
      const float* base = &Al[row*132 + ks*32 + kg*4];
      float4 f0 = *(const float4*)base;
      float4 f1 = *(const float4*)(base + 16);
      float vs[8] = {f0.x,f0.y,f0.z,f0.w,f1.x,f1.y,f1.z,f1.w};
      #pragma unroll
      for(int e=0;e<8;e++){
        float x = vs[e];
        unsigned int u = __float_as_uint(x);
        unsigned int rh = u + 0x7FFF + ((u>>16)&1);
        unsigned short hh = (unsigned short)(rh>>16);
        float fh = __uint_as_float((unsigned int)hh << 16);
        float r1 = x - fh;
        unsigned int u1 = __float_as_uint(r1);
        unsigned int rm = u1 + 0x7FFF + ((u1>>16)&1);
        unsigned short mv = (unsigned short)(rm>>16);
        float fm = __uint_as_float((unsigned int)mv << 16);
        float r2 = r1 - fm;
        unsigned int u2 = __float_as_uint(r2);
        unsigned int rl = u2 + 0x7FFF + ((u2>>16)&1);
        unsigned short lv = (unsigned short)(rl>>16);
        ah[mf][e]  = (short)hh;
        am[mf][e]  = (short)mv;
        alo[mf][e] = (short)lv;
      }
    }
    #pragma unroll
    for(int nf=0;nf<NF;nf++){
      size_t widx = ((size_t)(ks*NF + nf)*64 + lane)*8;
      short8 wh = *(const short8*)&Wh[widx];
      short8 wm = *(const short8*)&Wm[widx];
      short8 wl = *(const short8*)&Wl[widx];
      #pragma unroll
      for(int mf=0;mf<2;mf++){
        acc[mf][nf] = __builtin_amdgcn_mfma_f32_16x16x32_bf16(ah[mf],  wh, acc[mf][nf], 0,0,0);
        acc[mf][nf] = __builtin_amdgcn_mfma_f32_16x16x32_bf16(ah[mf],  wm, acc[mf][nf], 0,0,0);
        acc[mf][nf] = __builtin_amdgcn_mfma_f32_16x16x32_bf16(am[mf],  wh, acc[mf][nf], 0,0,0);
        acc[mf][nf] = __builtin_amdgcn_mfma_f32_16x16x32_bf16(ah[mf],  wl, acc[mf][nf], 0,0,0);
        acc[mf][nf] = __builtin_amdgcn_mfma_f32_16x16x32_bf16(alo[mf], wh, acc[mf][nf], 0,0,0);
        acc[mf][nf] = __builtin_amdgcn_mfma_f32_16x16x32_bf16(am[mf],  wm, acc[mf][nf], 0,0,0);
      }
    }
  }
  // epilogue: C/D layout col = lane&15, row = kg*4 + reg
  const int N = NF*16;
  #pragma unroll
  for(int mf=0;mf<2;mf++){
    #pragma unroll
    for(int nf=0;nf<NF;nf++){
      int gcol = nf*16 + m15;
      float bv = bias[gcol];
      #pragma unroll
      for(int r=0;r<4;r++){
        int grow = rowbase + w*32 + mf*16 + kg*4 + r;
        if(grow < nrows){
          float v = acc[mf][nf][r] + bv;
          if(GELU) v = gelu_f(v);
          C[(size_t)grow*N + gcol] = v;
        }
      }
    }
  }
}

// ---------- aggregation: one wave per node, rc-pair per half-wave, 1-deep prefetch
template<bool FIRST>
__global__ __launch_bounds__(256) void k_agg(const float* __restrict__ hin, const float* __restrict__ emb,
                       const float4* __restrict__ em4, const int* __restrict__ rs,
                       const int* __restrict__ eid, const int* __restrict__ esrc,
                       const float* __restrict__ epsp, float* __restrict__ tout){
  int t = threadIdx.x;
  int w = t >> 6;
  int lane = t & 63;
  int half = lane >> 5;
  int l32 = lane & 31;
  int n = blockIdx.x*4 + w;
  int d0 = l32*4;
  int rc0 = half*2, rc1 = rc0+1;
  float4 acc0 = {0.f,0.f,0.f,0.f}, acc1 = {0.f,0.f,0.f,0.f};
  int jb = rs[n], je = rs[n+1];
  if(jb < je){
    int e = eid[jb], s = esrc[jb];
    float4 ev = *(const float4*)&emb[(size_t)e*H + d0];
    float4 m  = em4[e];
    float4 h0, h1;
    if(FIRST){
      h0 = *(const float4*)&hin[(size_t)s*H + d0];
      h1 = h0;
    } else {
      h0 = *(const float4*)&hin[((size_t)rc0*NN + s)*H + d0];
      h1 = *(const float4*)&hin[((size_t)rc1*NN + s)*H + d0];
    }
    for(int j=jb; j<je; j++){
      float4 ev_n = {0,0,0,0}, m_n = {0,0,0,0}, h0_n = {0,0,0,0}, h1_n = {0,0,0,0};
      if(j+1 < je){
        int e2 = eid[j+1], s2 = esrc[j+1];
        ev_n = *(const float4*)&emb[(size_t)e2*H + d0];
        m_n  = em4[e2];
        if(FIRST){
          h0_n = *(const float4*)&hin[(size_t)s2*H + d0];
          h1_n = h0_n;
        } else {
          h0_n = *(const float4*)&hin[((size_t)rc0*NN + s2)*H + d0];
          h1_n = *(const float4*)&hin[((size_t)rc1*NN + s2)*H + d0];
        }
      }
      float m0 = half ? m.z : m.x;
      float m1 = half ? m.w : m.y;
      if(FIRST){
        float gx = gelu_f(h0.x+ev.x);
        float gy = gelu_f(h0.y+ev.y);
        float gz = gelu_f(h0.z+ev.z);
        float gw = gelu_f(h0.w+ev.w);
        acc0.x += gx*m0; acc0.y += gy*m0; acc0.z += gz*m0; acc0.w += gw*m0;
        acc1.x += gx*m1; acc1.y += gy*m1; acc1.z += gz*m1; acc1.w += gw*m1;
      } else {
        acc0.x += gelu_f(h0.x+ev.x)*m0;
        acc0.y += gelu_f(h0.y+ev.y)*m0;
        acc0.z += gelu_f(h0.z+ev.z)*m0;
        acc0.w += gelu_f(h0.w+ev.w)*m0;
        acc1.x += gelu_f(h1.x+ev.x)*m1;
        acc1.y += gelu_f(h1.y+ev.y)*m1;
        acc1.z += gelu_f(h1.z+ev.z)*m1;
        acc1.w += gelu_f(h1.w+ev.w)*m1;
      }
      ev = ev_n; m = m_n; h0 = h0_n; h1 = h1_n;
    }
  }
  float e1 = 1.0f + epsp[0];
  {
    const float* hb = FIRST ? (hin + (size_t)n*H) : (hin + ((size_t)rc0*NN + n)*H);
    float4 hv = *(const float4*)&hb[d0];
    float4 o;
    o.x = e1*hv.x + acc0.x; o.y = e1*hv.y + acc0.y;
    o.z = e1*hv.z + acc0.z; o.w = e1*hv.w + acc0.w;
    *(float4*)&tout[((size_t)rc0*NN + n)*H + d0] = o;
  }
  {
    const float* hb = FIRST ? (hin + (size_t)n*H) : (hin + ((size_t)rc1*NN + n)*H);
    float4 hv = *(const float4*)&hb[d0];
    float4 o;
    o.x = e1*hv.x + acc1.x; o.y = e1*hv.y + acc1.y;
    o.z = e1*hv.z + acc1.z; o.w = e1*hv.w + acc1.w;
    *(float4*)&tout[((size_t)rc1*NN + n)*H + d0] = o;
  }
}

// ---------- deterministic masked segment mean
__global__ __launch_bounds__(64) void k_pool(const float* __restrict__ y, const float* __restrict__ nm,
                       const int* __restrict__ gs, float* __restrict__ out){
  int seg = blockIdx.x;
  int rc = seg / NG;
  int g  = seg - rc*NG;
  int c  = threadIdx.x;
  int nb = gs[g], ne = gs[g+1];
  float num = 0.f, den = 0.f;
  for(int n=nb; n<ne; n++){
    float w = nm[rc*NN + n];
    num += y[((size_t)rc*NN + n)*OUTF + c] * w;
    den += w;
  }
  out[seg*OUTF + c] = num / fmaxf(den, 1e-12f);
}

extern "C" void kernel_launch(void* const* d_in, const int* in_sizes, int n_in,
                              void* d_out, int out_size, void* d_ws, size_t ws_size,
                              hipStream_t stream){
  const float* x         = (const float*)d_in[0];
  const float* edge_attr = (const float*)d_in[1];
  const float* node_mask = (const float*)d_in[2];
  const float* bond_W    = (const float*)d_in[3];
  const float* bond_b    = (const float*)d_in[4];
  const float* epsv      = (const float*)d_in[5];
  const float* conv_W1   = (const float*)d_in[6];
  const float* conv_b1   = (const float*)d_in[7];
  const float* conv_W2   = (const float*)d_in[8];
  const float* conv_b2   = (const float*)d_in[9];
  const float* mlp_W1    = (const float*)d_in[10];
  const float* mlp_b1    = (const float*)d_in[11];
  const float* mlp_W2    = (const float*)d_in[12];
  const float* mlp_b2    = (const float*)d_in[13];
  const int*   eidx      = (const int*)d_in[14];
  const int*   batch     = (const int*)d_in[15];
  const int* srcp = eidx;
  const int* dstp = eidx + EE;

  char* p = (char*)d_ws;
  auto alloc = [&](size_t bytes)->char*{
    char* r = p; p += (bytes + 255) & ~size_t(255); return r;
  };
  float*  h    = (float*) alloc((size_t)RCN*NN*H*4);
  float*  tbuf = (float*) alloc((size_t)RCN*NN*H*4);
  float*  u    = (float*) alloc((size_t)RCN*NN*H*4);
  float*  emb  = (float*) alloc((size_t)EE*H*4);
  float4* em4  = (float4*)alloc((size_t)EE*16);
  float*  y    = (float*) alloc((size_t)RCN*NN*OUTF*4);
  int*    cnt  = (int*)   alloc((size_t)NN*4);
  int*    rs   = (int*)   alloc((size_t)(NN+1)*4);
  int*    cur  = (int*)   alloc((size_t)NN*4);
  int*    eid  = (int*)   alloc((size_t)EE*4);
  int*    esrc = (int*)   alloc((size_t)EE*4);
  int*    gs   = (int*)   alloc((size_t)(NG+1)*4);
  // split-W buffers (bf16 frag-linear): per family h/m/l planes
  unsigned short* WBh  = (unsigned short*)alloc((size_t)3*16384*2);
  unsigned short* WBm  = (unsigned short*)alloc((size_t)3*16384*2);
  unsigned short* WBl  = (unsigned short*)alloc((size_t)3*16384*2);
  unsigned short* WC1h = (unsigned short*)alloc((size_t)3*16384*2);
  unsigned short* WC1m = (unsigned short*)alloc((size_t)3*16384*2);
  unsigned short* WC1l = (unsigned short*)alloc((size_t)3*16384*2);
  unsigned short* WC2h = (unsigned short*)alloc((size_t)3*16384*2);
  unsigned short* WC2m = (unsigned short*)alloc((size_t)3*16384*2);
  unsigned short* WC2l = (unsigned short*)alloc((size_t)3*16384*2);
  unsigned short* WM1h = (unsigned short*)alloc((size_t)16384*2);
  unsigned short* WM1m = (unsigned short*)alloc((size_t)16384*2);
  unsigned short* WM1l = (unsigned short*)alloc((size_t)16384*2);
  unsigned short* WM2h = (unsigned short*)alloc((size_t)8192*2);
  unsigned short* WM2m = (unsigned short*)alloc((size_t)8192*2);
  unsigned short* WM2l = (unsigned short*)alloc((size_t)8192*2);
  if((size_t)(p - (char*)d_ws) > ws_size) return;

  hipMemsetAsync(cnt, 0, (size_t)NN*4, stream);

  k_edge_mask<<<(EE+255)/256, 256, 0, stream>>>(srcp, dstp, node_mask, em4);
  k_hist     <<<(EE+255)/256, 256, 0, stream>>>(dstp, cnt);
  k_scan     <<<1, 1024, 0, stream>>>(cnt, rs, cur);
  k_fill     <<<(EE+255)/256, 256, 0, stream>>>(dstp, cur, eid);
  k_sortcsr  <<<(NN+255)/256, 256, 0, stream>>>(rs, eid, srcp, esrc);
  k_gbounds  <<<1, 128, 0, stream>>>(batch, gs);
  k_splitW   <<<192, 256, 0, stream>>>(bond_W,  WBh,  WBm,  WBl,  3, 128);
  k_splitW   <<<192, 256, 0, stream>>>(conv_W1, WC1h, WC1m, WC1l, 3, 128);
  k_splitW   <<<192, 256, 0, stream>>>(conv_W2, WC2h, WC2m, WC2l, 3, 128);
  k_splitW   <<<64,  256, 0, stream>>>(mlp_W1,  WM1h, WM1m, WM1l, 1, 128);
  k_splitW   <<<32,  256, 0, stream>>>(mlp_W2,  WM2h, WM2m, WM2l, 1, 64);

  const int NROWS = RCN*NN;
  const int GB_E = EE/128;             // 1250
  const int GB_N = (NROWS+127)/128;    // 313
  for(int l=0; l<3; l++){
    size_t wo = (size_t)l*16384;
    k_mgemm<8,false><<<GB_E, 256, 0, stream>>>(edge_attr, WBh+wo, WBm+wo, WBl+wo,
                                               bond_b + l*H, emb, EE);
    if(l == 0)
      k_agg<true ><<<NN/4, 256, 0, stream>>>(x, emb, em4, rs, eid, esrc, epsv + l, tbuf);
    else
      k_agg<false><<<NN/4, 256, 0, stream>>>(h, emb, em4, rs, eid, esrc, epsv + l, tbuf);
    k_mgemm<8,true><<<GB_N, 256, 0, stream>>>(tbuf, WC1h+wo, WC1m+wo, WC1l+wo,
                                              conv_b1 + l*H, u, NROWS);
    k_mgemm<8,true><<<GB_N, 256, 0, stream>>>(u, WC2h+wo, WC2m+wo, WC2l+wo,
                                              conv_b2 + l*H, h, NROWS);
  }
  k_mgemm<8,true><<<GB_N, 256, 0, stream>>>(h, WM1h, WM1m, WM1l, mlp_b1, u, NROWS);
  k_mgemm<4,false><<<GB_N, 256, 0, stream>>>(u, WM2h, WM2m, WM2l, mlp_b2, y, NROWS);
  k_pool<<<DSEG, 64, 0, stream>>>(y, node_mask, gs, (float*)d_out);
}

// Round 7
// 778.258 us; speedup vs baseline: 1.5872x; 1.1511x over previous
//
#include <hip/hip_runtime.h>

constexpr int H    = 128;
constexpr int NN   = 10000;
constexpr int EE   = 160000;
constexpr int RCN  = 4;      // R*C
constexpr int NG   = 64;     // graphs per replica
constexpr int OUTF = 64;
constexpr int DSEG = 256;    // RCN*NG

using short8 = __attribute__((ext_vector_type(8))) short;
using f32x4  = __attribute__((ext_vector_type(4))) float;

// Exact-GELU via A&S 7.1.26 erf (|err|<=1.5e-7 abs; below the bf16x3 GEMM error
// already absorbed by the harness tolerance). ~16 VALU vs ~60-70 for OCML erff.
__device__ __forceinline__ float gelu_f(float x){
  float z  = x*0.70710678118654752440f;
  float az = fabsf(z);
  float t  = __builtin_amdgcn_rcpf(fmaf(az, 0.3275911f, 1.0f));
  float e  = __expf(-z*z);
  float poly = fmaf(fmaf(fmaf(fmaf(1.061405429f, t, -1.453152027f),
                              t, 1.421413741f),
                         t, -0.284496736f),
                    t, 0.254829592f) * t;
  float er = fmaf(-poly, e, 1.0f);     // erf(|z|)
  er = copysignf(er, z);
  return 0.5f*x*(1.0f + er);
}

// ---------- edge mask
__global__ void k_edge_mask(const int* __restrict__ src, const int* __restrict__ dst,
                            const float* __restrict__ nm, float4* __restrict__ em4){
  int e = blockIdx.x*256 + threadIdx.x;
  if(e >= EE) return;
  int s = src[e], d = dst[e];
  float4 m;
  m.x = nm[0*NN+s]*nm[0*NN+d];
  m.y = nm[1*NN+s]*nm[1*NN+d];
  m.z = nm[2*NN+s]*nm[2*NN+d];
  m.w = nm[3*NN+s]*nm[3*NN+d];
  em4[e] = m;
}

// ---------- CSR build
__global__ void k_hist(const int* __restrict__ dst, int* __restrict__ cnt){
  int e = blockIdx.x*256 + threadIdx.x;
  if(e < EE) atomicAdd(&cnt[dst[e]], 1);
}

__global__ __launch_bounds__(1024) void k_scan(const int* __restrict__ cnt,
                                               int* __restrict__ rs, int* __restrict__ cur){
  __shared__ int part[1024];
  int t = threadIdx.x;
  const int CH = 10;
  int base = t*CH;
  int s = 0;
  #pragma unroll
  for(int j=0;j<CH;j++){ int i = base+j; if(i<NN) s += cnt[i]; }
  part[t] = s;
  __syncthreads();
  for(int off=1; off<1024; off<<=1){
    int v = (t>=off) ? part[t-off] : 0;
    __syncthreads();
    part[t] += v;
    __syncthreads();
  }
  int run = (t==0) ? 0 : part[t-1];
  #pragma unroll
  for(int j=0;j<CH;j++){
    int i = base+j;
    if(i<NN){ rs[i] = run; cur[i] = run; run += cnt[i]; }
  }
  if(t == 1023) rs[NN] = part[1023];
}

__global__ void k_fill(const int* __restrict__ dst,
                       int* __restrict__ cur, int* __restrict__ eid){
  int e = blockIdx.x*256 + threadIdx.x;
  if(e >= EE) return;
  int p = atomicAdd(&cur[dst[e]], 1);
  eid[p] = e;
}

__global__ void k_sortcsr(const int* __restrict__ rs, int* __restrict__ eid,
                          const int* __restrict__ src, int* __restrict__ esrc){
  int n = blockIdx.x*256 + threadIdx.x;
  if(n >= NN) return;
  int jb = rs[n], je = rs[n+1];
  for(int j=jb+1; j<je; j++){
    int v = eid[j];
    int k = j-1;
    while(k >= jb && eid[k] > v){ eid[k+1] = eid[k]; k--; }
    eid[k+1] = v;
  }
  for(int j=jb; j<je; j++) esrc[j] = src[eid[j]];
}

__global__ void k_gbounds(const int* __restrict__ batch, int* __restrict__ gs){
  int g = threadIdx.x;
  if(g > NG) return;
  if(g == NG){ gs[NG] = NN; return; }
  int lo = 0, hi = NN;
  while(lo < hi){
    int mid = (lo+hi)>>1;
    if(batch[mid] < g) lo = mid+1; else hi = mid;
  }
  gs[g] = lo;
}

// ---------- split W (fp32 -> 3x bf16, RNE) into MFMA B-fragment-linear layout
// B-frag for 16x16x32: lane = (n%16) + 16*kg, elem e: k = 16*(e>>2) + 4*kg + (e&3)
__global__ void k_splitW(const float* __restrict__ W, unsigned short* __restrict__ oh,
                         unsigned short* __restrict__ om, unsigned short* __restrict__ ol,
                         int nmat, int N){
  int tid = blockIdx.x*256 + threadIdx.x;
  int total = nmat*128*N;
  if(tid >= total) return;
  int mat = tid / (128*N);
  int rem = tid - mat*(128*N);
  int k = rem / N;
  int n = rem - k*N;
  int NF = N >> 4;
  int ks = k >> 5, kk = k & 31;
  int nf = n >> 4;
  int lane = (n & 15) + 16*((kk & 15) >> 2);
  int e = 4*(kk >> 4) + (kk & 3);
  size_t idx = (size_t)mat*128*N + ((size_t)(ks*NF + nf)*64 + lane)*8 + e;
  float x = W[tid];
  unsigned int u = __float_as_uint(x);
  unsigned int rh = u + 0x7FFF + ((u>>16)&1);
  unsigned short hh = (unsigned short)(rh>>16);
  float fh = __uint_as_float((unsigned int)hh << 16);
  float r1 = x - fh;
  unsigned int u1 = __float_as_uint(r1);
  unsigned int rm = u1 + 0x7FFF + ((u1>>16)&1);
  unsigned short mm = (unsigned short)(rm>>16);
  float fm = __uint_as_float((unsigned int)mm << 16);
  float r2 = r1 - fm;
  unsigned int u2 = __float_as_uint(r2);
  unsigned int rl = u2 + 0x7FFF + ((u2>>16)&1);
  unsigned short ll = (unsigned short)(rl>>16);
  oh[idx] = hh; om[idx] = mm; ol[idx] = ll;
}

// ---------- MFMA GEMM: C = act(A[nrows x 128] @ W[128 x N] + b), bf16x3 split (6 terms)
// 128-row tile per block, 4 waves, each wave: 32 rows x N cols.
// W fragments prefetched 2 steps ahead (flattened (ks,nf) loop).
template<int NF, bool GELU>
__global__ __launch_bounds__(256) void k_mgemm(const float* __restrict__ A,
    const unsigned short* __restrict__ Wh, const unsigned short* __restrict__ Wm,
    const unsigned short* __restrict__ Wl, const float* __restrict__ bias,
    float* __restrict__ C, int nrows){
  __shared__ float Al[128*132];   // 66 KB -> 2 blocks/CU
  int t = threadIdx.x;
  int rowbase = blockIdx.x*128;
  #pragma unroll
  for(int i=0;i<16;i++){
    int idx = i*256 + t;
    int r = idx >> 5, c4 = idx & 31;
    int gr = rowbase + r;
    float4 v = {0.f,0.f,0.f,0.f};
    if(gr < nrows) v = *(const float4*)&A[(size_t)gr*H + c4*4];
    *(float4*)&Al[r*132 + c4*4] = v;
  }
  __syncthreads();
  int w = t >> 6, lane = t & 63;
  int m15 = lane & 15, kg = lane >> 4;

  const int SMAX = 4*NF - 1;
  auto ldW = [&](int s, short8* d){
    size_t widx = ((size_t)s*64 + lane)*8;
    d[0] = *(const short8*)&Wh[widx];
    d[1] = *(const short8*)&Wm[widx];
    d[2] = *(const short8*)&Wl[widx];
  };

  f32x4 acc[2][NF];
  #pragma unroll
  for(int mf=0;mf<2;mf++)
    #pragma unroll
    for(int nf=0;nf<NF;nf++) acc[mf][nf] = (f32x4){0.f,0.f,0.f,0.f};

  short8 cw[3], nw[3];
  ldW(0, cw);
  ldW(1 <= SMAX ? 1 : SMAX, nw);

  for(int ks=0;ks<4;ks++){
    short8 ah[2], am[2], alo[2];
    #pragma unroll
    for(int mf=0;mf<2;mf++){
      int row = w*32 + mf*16 + m15;
      const float* base = &Al[row*132 + ks*32 + kg*4];
      float4 f0 = *(const float4*)base;
      float4 f1 = *(const float4*)(base + 16);
      float vs[8] = {f0.x,f0.y,f0.z,f0.w,f1.x,f1.y,f1.z,f1.w};
      #pragma unroll
      for(int e=0;e<8;e++){
        float x = vs[e];
        unsigned int u = __float_as_uint(x);
        unsigned int rh = u + 0x7FFF + ((u>>16)&1);
        unsigned short hh = (unsigned short)(rh>>16);
        float fh = __uint_as_float((unsigned int)hh << 16);
        float r1 = x - fh;
        unsigned int u1 = __float_as_uint(r1);
        unsigned int rm = u1 + 0x7FFF + ((u1>>16)&1);
        unsigned short mv = (unsigned short)(rm>>16);
        float fm = __uint_as_float((unsigned int)mv << 16);
        float r2 = r1 - fm;
        unsigned int u2 = __float_as_uint(r2);
        unsigned int rl = u2 + 0x7FFF + ((u2>>16)&1);
        unsigned short lv = (unsigned short)(rl>>16);
        ah[mf][e]  = (short)hh;
        am[mf][e]  = (short)mv;
        alo[mf][e] = (short)lv;
      }
    }
    #pragma unroll
    for(int nf=0;nf<NF;nf++){
      int s = ks*NF + nf;
      short8 pw[3];
      ldW(s+2 <= SMAX ? s+2 : SMAX, pw);   // 2-deep prefetch
      #pragma unroll
      for(int mf=0;mf<2;mf++){
        acc[mf][nf] = __builtin_amdgcn_mfma_f32_16x16x32_bf16(ah[mf],  cw[0], acc[mf][nf], 0,0,0);
        acc[mf][nf] = __builtin_amdgcn_mfma_f32_16x16x32_bf16(ah[mf],  cw[1], acc[mf][nf], 0,0,0);
        acc[mf][nf] = __builtin_amdgcn_mfma_f32_16x16x32_bf16(am[mf],  cw[0], acc[mf][nf], 0,0,0);
        acc[mf][nf] = __builtin_amdgcn_mfma_f32_16x16x32_bf16(ah[mf],  cw[2], acc[mf][nf], 0,0,0);
        acc[mf][nf] = __builtin_amdgcn_mfma_f32_16x16x32_bf16(alo[mf], cw[0], acc[mf][nf], 0,0,0);
        acc[mf][nf] = __builtin_amdgcn_mfma_f32_16x16x32_bf16(am[mf],  cw[1], acc[mf][nf], 0,0,0);
      }
      cw[0]=nw[0]; cw[1]=nw[1]; cw[2]=nw[2];
      nw[0]=pw[0]; nw[1]=pw[1]; nw[2]=pw[2];
    }
  }
  // epilogue: C/D layout col = lane&15, row = kg*4 + reg
  const int N = NF*16;
  #pragma unroll
  for(int mf=0;mf<2;mf++){
    #pragma unroll
    for(int nf=0;nf<NF;nf++){
      int gcol = nf*16 + m15;
      float bv = bias[gcol];
      #pragma unroll
      for(int r=0;r<4;r++){
        int grow = rowbase + w*32 + mf*16 + kg*4 + r;
        if(grow < nrows){
          float v = acc[mf][nf][r] + bv;
          if(GELU) v = gelu_f(v);
          C[(size_t)grow*N + gcol] = v;
        }
      }
    }
  }
}

// ---------- aggregation: one wave per node, rc-pair per half-wave, 1-deep prefetch
template<bool FIRST>
__global__ __launch_bounds__(256) void k_agg(const float* __restrict__ hin, const float* __restrict__ emb,
                       const float4* __restrict__ em4, const int* __restrict__ rs,
                       const int* __restrict__ eid, const int* __restrict__ esrc,
                       const float* __restrict__ epsp, float* __restrict__ tout){
  int t = threadIdx.x;
  int w = t >> 6;
  int lane = t & 63;
  int half = lane >> 5;
  int l32 = lane & 31;
  int n = blockIdx.x*4 + w;
  int d0 = l32*4;
  int rc0 = half*2, rc1 = rc0+1;
  float4 acc0 = {0.f,0.f,0.f,0.f}, acc1 = {0.f,0.f,0.f,0.f};
  int jb = rs[n], je = rs[n+1];
  if(jb < je){
    int e = eid[jb], s = esrc[jb];
    float4 ev = *(const float4*)&emb[(size_t)e*H + d0];
    float4 m  = em4[e];
    float4 h0, h1;
    if(FIRST){
      h0 = *(const float4*)&hin[(size_t)s*H + d0];
      h1 = h0;
    } else {
      h0 = *(const float4*)&hin[((size_t)rc0*NN + s)*H + d0];
      h1 = *(const float4*)&hin[((size_t)rc1*NN + s)*H + d0];
    }
    for(int j=jb; j<je; j++){
      float4 ev_n = {0,0,0,0}, m_n = {0,0,0,0}, h0_n = {0,0,0,0}, h1_n = {0,0,0,0};
      if(j+1 < je){
        int e2 = eid[j+1], s2 = esrc[j+1];
        ev_n = *(const float4*)&emb[(size_t)e2*H + d0];
        m_n  = em4[e2];
        if(FIRST){
          h0_n = *(const float4*)&hin[(size_t)s2*H + d0];
          h1_n = h0_n;
        } else {
          h0_n = *(const float4*)&hin[((size_t)rc0*NN + s2)*H + d0];
          h1_n = *(const float4*)&hin[((size_t)rc1*NN + s2)*H + d0];
        }
      }
      float m0 = half ? m.z : m.x;
      float m1 = half ? m.w : m.y;
      if(FIRST){
        float gx = gelu_f(h0.x+ev.x);
        float gy = gelu_f(h0.y+ev.y);
        float gz = gelu_f(h0.z+ev.z);
        float gw = gelu_f(h0.w+ev.w);
        acc0.x += gx*m0; acc0.y += gy*m0; acc0.z += gz*m0; acc0.w += gw*m0;
        acc1.x += gx*m1; acc1.y += gy*m1; acc1.z += gz*m1; acc1.w += gw*m1;
      } else {
        acc0.x += gelu_f(h0.x+ev.x)*m0;
        acc0.y += gelu_f(h0.y+ev.y)*m0;
        acc0.z += gelu_f(h0.z+ev.z)*m0;
        acc0.w += gelu_f(h0.w+ev.w)*m0;
        acc1.x += gelu_f(h1.x+ev.x)*m1;
        acc1.y += gelu_f(h1.y+ev.y)*m1;
        acc1.z += gelu_f(h1.z+ev.z)*m1;
        acc1.w += gelu_f(h1.w+ev.w)*m1;
      }
      ev = ev_n; m = m_n; h0 = h0_n; h1 = h1_n;
    }
  }
  float e1 = 1.0f + epsp[0];
  {
    const float* hb = FIRST ? (hin + (size_t)n*H) : (hin + ((size_t)rc0*NN + n)*H);
    float4 hv = *(const float4*)&hb[d0];
    float4 o;
    o.x = e1*hv.x + acc0.x; o.y = e1*hv.y + acc0.y;
    o.z = e1*hv.z + acc0.z; o.w = e1*hv.w + acc0.w;
    *(float4*)&tout[((size_t)rc0*NN + n)*H + d0] = o;
  }
  {
    const float* hb = FIRST ? (hin + (size_t)n*H) : (hin + ((size_t)rc1*NN + n)*H);
    float4 hv = *(const float4*)&hb[d0];
    float4 o;
    o.x = e1*hv.x + acc1.x; o.y = e1*hv.y + acc1.y;
    o.z = e1*hv.z + acc1.z; o.w = e1*hv.w + acc1.w;
    *(float4*)&tout[((size_t)rc1*NN + n)*H + d0] = o;
  }
}

// ---------- deterministic masked segment mean
__global__ __launch_bounds__(64) void k_pool(const float* __restrict__ y, const float* __restrict__ nm,
                       const int* __restrict__ gs, float* __restrict__ out){
  int seg = blockIdx.x;
  int rc = seg / NG;
  int g  = seg - rc*NG;
  int c  = threadIdx.x;
  int nb = gs[g], ne = gs[g+1];
  float num = 0.f, den = 0.f;
  for(int n=nb; n<ne; n++){
    float w = nm[rc*NN + n];
    num += y[((size_t)rc*NN + n)*OUTF + c] * w;
    den += w;
  }
  out[seg*OUTF + c] = num / fmaxf(den, 1e-12f);
}

extern "C" void kernel_launch(void* const* d_in, const int* in_sizes, int n_in,
                              void* d_out, int out_size, void* d_ws, size_t ws_size,
                              hipStream_t stream){
  const float* x         = (const float*)d_in[0];
  const float* edge_attr = (const float*)d_in[1];
  const float* node_mask = (const float*)d_in[2];
  const float* bond_W    = (const float*)d_in[3];
  const float* bond_b    = (const float*)d_in[4];
  const float* epsv      = (const float*)d_in[5];
  const float* conv_W1   = (const float*)d_in[6];
  const float* conv_b1   = (const float*)d_in[7];
  const float* conv_W2   = (const float*)d_in[8];
  const float* conv_b2   = (const float*)d_in[9];
  const float* mlp_W1    = (const float*)d_in[10];
  const float* mlp_b1    = (const float*)d_in[11];
  const float* mlp_W2    = (const float*)d_in[12];
  const float* mlp_b2    = (const float*)d_in[13];
  const int*   eidx      = (const int*)d_in[14];
  const int*   batch     = (const int*)d_in[15];
  const int* srcp = eidx;
  const int* dstp = eidx + EE;

  char* p = (char*)d_ws;
  auto alloc = [&](size_t bytes)->char*{
    char* r = p; p += (bytes + 255) & ~size_t(255); return r;
  };
  float*  h    = (float*) alloc((size_t)RCN*NN*H*4);
  float*  tbuf = (float*) alloc((size_t)RCN*NN*H*4);
  float*  u    = (float*) alloc((size_t)RCN*NN*H*4);
  float*  emb  = (float*) alloc((size_t)EE*H*4);
  float4* em4  = (float4*)alloc((size_t)EE*16);
  float*  y    = (float*) alloc((size_t)RCN*NN*OUTF*4);
  int*    cnt  = (int*)   alloc((size_t)NN*4);
  int*    rs   = (int*)   alloc((size_t)(NN+1)*4);
  int*    cur  = (int*)   alloc((size_t)NN*4);
  int*    eid  = (int*)   alloc((size_t)EE*4);
  int*    esrc = (int*)   alloc((size_t)EE*4);
  int*    gs   = (int*)   alloc((size_t)(NG+1)*4);
  // split-W buffers (bf16 frag-linear): per family h/m/l planes
  unsigned short* WBh  = (unsigned short*)alloc((size_t)3*16384*2);
  unsigned short* WBm  = (unsigned short*)alloc((size_t)3*16384*2);
  unsigned short* WBl  = (unsigned short*)alloc((size_t)3*16384*2);
  unsigned short* WC1h = (unsigned short*)alloc((size_t)3*16384*2);
  unsigned short* WC1m = (unsigned short*)alloc((size_t)3*16384*2);
  unsigned short* WC1l = (unsigned short*)alloc((size_t)3*16384*2);
  unsigned short* WC2h = (unsigned short*)alloc((size_t)3*16384*2);
  unsigned short* WC2m = (unsigned short*)alloc((size_t)3*16384*2);
  unsigned short* WC2l = (unsigned short*)alloc((size_t)3*16384*2);
  unsigned short* WM1h = (unsigned short*)alloc((size_t)16384*2);
  unsigned short* WM1m = (unsigned short*)alloc((size_t)16384*2);
  unsigned short* WM1l = (unsigned short*)alloc((size_t)16384*2);
  unsigned short* WM2h = (unsigned short*)alloc((size_t)8192*2);
  unsigned short* WM2m = (unsigned short*)alloc((size_t)8192*2);
  unsigned short* WM2l = (unsigned short*)alloc((size_t)8192*2);
  if((size_t)(p - (char*)d_ws) > ws_size) return;

  hipMemsetAsync(cnt, 0, (size_t)NN*4, stream);

  k_edge_mask<<<(EE+255)/256, 256, 0, stream>>>(srcp, dstp, node_mask, em4);
  k_hist     <<<(EE+255)/256, 256, 0, stream>>>(dstp, cnt);
  k_scan     <<<1, 1024, 0, stream>>>(cnt, rs, cur);
  k_fill     <<<(EE+255)/256, 256, 0, stream>>>(dstp, cur, eid);
  k_sortcsr  <<<(NN+255)/256, 256, 0, stream>>>(rs, eid, srcp, esrc);
  k_gbounds  <<<1, 128, 0, stream>>>(batch, gs);
  k_splitW   <<<192, 256, 0, stream>>>(bond_W,  WBh,  WBm,  WBl,  3, 128);
  k_splitW   <<<192, 256, 0, stream>>>(conv_W1, WC1h, WC1m, WC1l, 3, 128);
  k_splitW   <<<192, 256, 0, stream>>>(conv_W2, WC2h, WC2m, WC2l, 3, 128);
  k_splitW   <<<64,  256, 0, stream>>>(mlp_W1,  WM1h, WM1m, WM1l, 1, 128);
  k_splitW   <<<32,  256, 0, stream>>>(mlp_W2,  WM2h, WM2m, WM2l, 1, 64);

  const int NROWS = RCN*NN;
  const int GB_E = EE/128;             // 1250
  const int GB_N = (NROWS+127)/128;    // 313
  for(int l=0; l<3; l++){
    size_t wo = (size_t)l*16384;
    k_mgemm<8,false><<<GB_E, 256, 0, stream>>>(edge_attr, WBh+wo, WBm+wo, WBl+wo,
                                               bond_b + l*H, emb, EE);
    if(l == 0)
      k_agg<true ><<<NN/4, 256, 0, stream>>>(x, emb, em4, rs, eid, esrc, epsv + l, tbuf);
    else
      k_agg<false><<<NN/4, 256, 0, stream>>>(h, emb, em4, rs, eid, esrc, epsv + l, tbuf);
    k_mgemm<8,true><<<GB_N, 256, 0, stream>>>(tbuf, WC1h+wo, WC1m+wo, WC1l+wo,
                                              conv_b1 + l*H, u, NROWS);
    k_mgemm<8,true><<<GB_N, 256, 0, stream>>>(u, WC2h+wo, WC2m+wo, WC2l+wo,
                                              conv_b2 + l*H, h, NROWS);
  }
  k_mgemm<8,true><<<GB_N, 256, 0, stream>>>(h, WM1h, WM1m, WM1l, mlp_b1, u, NROWS);
  k_mgemm<4,false><<<GB_N, 256, 0, stream>>>(u, WM2h, WM2m, WM2l, mlp_b2, y, NROWS);
  k_pool<<<DSEG, 64, 0, stream>>>(y, node_mask, gs, (float*)d_out);
}